// Round 11
// baseline (558.753 us; speedup 1.0000x reference)
//
#include <hip/hip_runtime.h>
#include <hip/hip_bf16.h>
#include <math.h>

#define NNODES 10000
#define NEDGES 160000
#define ETOT (NEDGES + NNODES)  // edges + self-loops
#define HEADS 7
#define CH 64
#define HC 448    // HEADS*CH
#define HCP 1024  // padded fused width: [xl 512 | xr 512], slot = half*512+c*8+h

typedef __attribute__((ext_vector_type(8))) short short8;
typedef __attribute__((ext_vector_type(4))) float floatx4;

__device__ __forceinline__ float bf_lo(unsigned u) {
  return __uint_as_float(u << 16);
}
__device__ __forceinline__ float bf_hi(unsigned u) {
  return __uint_as_float(u & 0xffff0000u);
}
__device__ __forceinline__ short f2bf(float v) {
  return __bfloat16_as_short(__float2bfloat16(v));
}

// ---------------------------------------------------------------------------
// Fused prep: x->bf16, W1/W2/W3 transpose->bf16, GAT weight pack, cnt init.
// ---------------------------------------------------------------------------
#define P0 2560000                // convert groups (4 floats each)
#define P1 (P0 + 512 * 1024)      // W1t entries
#define P2 (P1 + 256 * 512)      // W2t
#define P3 (P2 + 64 * 256)       // W3t
#define P4 (P3 + 5 * HCP * 64)    // Wgt
#define P5 (P4 + 5 * HCP)         // bg
#define P6 (P5 + NNODES)          // cnt init
#define PTOT P6

__global__ __launch_bounds__(256) void prep_kernel(
    const float* __restrict__ x, short* __restrict__ xb,
    const float* __restrict__ W1, short* __restrict__ W1t,
    const float* __restrict__ W2, short* __restrict__ W2t,
    const float* __restrict__ W3, short* __restrict__ W3t,
    const float* __restrict__ Wl, const float* __restrict__ Wr,
    const float* __restrict__ bl, short* __restrict__ Wgt,
    float* __restrict__ bg, int* __restrict__ cnt) {
  int idx = blockIdx.x * 256 + threadIdx.x;
  if (idx < P0) {
    float4 v = *(const float4*)&x[(size_t)idx * 4];
    short4 o;
    o.x = f2bf(v.x); o.y = f2bf(v.y); o.z = f2bf(v.z); o.w = f2bf(v.w);
    *(short4*)&xb[(size_t)idx * 4] = o;
  } else if (idx < P1) {
    int i = idx - P0;               // W1: K=1024, N=512
    int n = i / 1024, k = i % 1024;
    W1t[i] = f2bf(W1[(size_t)k * 512 + n]);
  } else if (idx < P2) {
    int i = idx - P1;               // W2: K=512, N=256
    int n = i / 512, k = i % 512;
    W2t[i] = f2bf(W2[(size_t)k * 256 + n]);
  } else if (idx < P3) {
    int i = idx - P2;               // W3: K=256, N=64
    int n = i / 256, k = i % 256;
    W3t[i] = f2bf(W3[(size_t)k * 64 + n]);
  } else if (idx < P4) {
    int i = idx - P3;               // Wgt[l][col'][k]
    int l = i / (HCP * 64);
    int rem = i % (HCP * 64);
    int col = rem / 64, k = rem % 64;
    int half = col >> 9;
    int within = col & 511;
    int c = within >> 3, h = within & 7;
    float v = 0.f;
    if (h < 7) {
      const float* W = half ? Wr : Wl;
      v = W[((size_t)l * 64 + k) * HC + h * 64 + c];
    }
    Wgt[i] = f2bf(v);
  } else if (idx < P5) {
    int i = idx - P4;
    int l = i >> 10, col = i & 1023;
    int half = col >> 9, within = col & 511;
    int c = within >> 3, h = within & 7;
    bg[i] = (!half && h < 7) ? bl[(size_t)l * HC + h * 64 + c] : 0.f;
  } else if (idx < P6) {
    cnt[idx - P5] = 1;  // self-loop
  }
}

// ---------------------------------------------------------------------------
// MFMA bf16 GEMM: C = act(A @ Bt^T + bias), bf16 row-major out.
// ---------------------------------------------------------------------------
template <int BM, int BN, int RELU>
__global__ __launch_bounds__(256) void mfma_gemm(
    const short* __restrict__ A, const short* __restrict__ Bt,
    const float* __restrict__ bias, short* __restrict__ C,
    int M, int K, int Nc) {
  __shared__ short As[BM * 64];
  __shared__ short Bs[BN * 64];
  constexpr int MI = BM / 32;
  constexpr int NJ = BN / 32;
  int tid = threadIdx.x;
  int lane = tid & 63, wave = tid >> 6;
  int wm = wave >> 1, wn = wave & 1;
  int row0 = blockIdx.x * BM, col0 = blockIdx.y * BN;
  floatx4 acc[MI][NJ] = {};

  for (int k0 = 0; k0 < K; k0 += 64) {
    #pragma unroll
    for (int i = 0; i < BM / 32; ++i) {
      int c = i * 4 + wave;
      int r = c * 8 + (lane >> 3);
      int k = (lane & 7) * 8;
      int grow = row0 + r;
      if (grow >= M) grow = M - 1;
      __builtin_amdgcn_global_load_lds(
          (const __attribute__((address_space(1))) void*)(A + (size_t)grow * K + k0 + k),
          (__attribute__((address_space(3))) void*)(As + c * 512), 16, 0, 0);
    }
    #pragma unroll
    for (int i = 0; i < BN / 32; ++i) {
      int c = i * 4 + wave;
      int r = c * 8 + (lane >> 3);
      int k = (lane & 7) * 8;
      int gcol = col0 + r;
      if (gcol >= Nc) gcol = Nc - 1;
      __builtin_amdgcn_global_load_lds(
          (const __attribute__((address_space(1))) void*)(Bt + (size_t)gcol * K + k0 + k),
          (__attribute__((address_space(3))) void*)(Bs + c * 512), 16, 0, 0);
    }
    __syncthreads();
    int lr = lane & 15, lq = lane >> 4;
    #pragma unroll
    for (int kk = 0; kk < 64; kk += 32) {
      short8 af[MI], bf[NJ];
      #pragma unroll
      for (int i = 0; i < MI; ++i)
        af[i] = *(const short8*)&As[(wm * (BM / 2) + i * 16 + lr) * 64 + kk + lq * 8];
      #pragma unroll
      for (int j = 0; j < NJ; ++j)
        bf[j] = *(const short8*)&Bs[(wn * (BN / 2) + j * 16 + lr) * 64 + kk + lq * 8];
      #pragma unroll
      for (int i = 0; i < MI; ++i)
        #pragma unroll
        for (int j = 0; j < NJ; ++j)
          acc[i][j] = __builtin_amdgcn_mfma_f32_16x16x32_bf16(
              af[i], bf[j], acc[i][j], 0, 0, 0);
    }
    __syncthreads();
  }

  int lr = lane & 15, lq = lane >> 4;
  #pragma unroll
  for (int j = 0; j < NJ; ++j) {
    int col = col0 + wn * (BN / 2) + j * 16 + lr;
    float bj = bias ? bias[col] : 0.f;
    #pragma unroll
    for (int i = 0; i < MI; ++i) {
      int rbase = row0 + wm * (BM / 2) + i * 16 + lq * 4;
      #pragma unroll
      for (int r = 0; r < 4; ++r) {
        int row = rbase + r;
        if (row < M) {
          float v = acc[i][j][r] + bj;
          if (RELU) v = fmaxf(v, 0.f);
          C[(size_t)row * Nc + col] = f2bf(v);
        }
      }
    }
  }
}

// ---------------------------------------------------------------------------
// CSR build (dst-grouped, self-loops included).
// ---------------------------------------------------------------------------
__global__ void hist_kernel(const int* __restrict__ ei, int* __restrict__ cnt) {
  int e = blockIdx.x * 256 + threadIdx.x;
  if (e < NEDGES) atomicAdd(&cnt[ei[NEDGES + e]], 1);
}

// single-block shuffle-based scan
__global__ __launch_bounds__(1024) void scan_kernel(
    const int* __restrict__ cnt, int* __restrict__ row_start,
    int* __restrict__ cursor) {
  __shared__ int wsum[16];
  int t = threadIdx.x;
  int lane = t & 63, w = t >> 6;
  int base = t * 10;
  int v[10], s = 0;
  #pragma unroll
  for (int i = 0; i < 10; ++i) {
    v[i] = (base + i < NNODES) ? cnt[base + i] : 0;
    s += v[i];
  }
  int incl = s;
  #pragma unroll
  for (int off = 1; off < 64; off <<= 1) {
    int o = __shfl_up(incl, off, 64);
    if (lane >= off) incl += o;
  }
  if (lane == 63) wsum[w] = incl;
  __syncthreads();
  if (w == 0) {
    int wv = (lane < 16) ? wsum[lane] : 0;
    #pragma unroll
    for (int off = 1; off < 16; off <<= 1) {
      int o = __shfl_up(wv, off, 64);
      if (lane >= off) wv += o;
    }
    if (lane < 16) wsum[lane] = wv;
  }
  __syncthreads();
  int woff = (w > 0) ? wsum[w - 1] : 0;
  int excl = woff + incl - s;
  #pragma unroll
  for (int i = 0; i < 10; ++i) {
    if (base + i < NNODES) {
      row_start[base + i] = excl;
      cursor[base + i] = excl;
    }
    excl += v[i];
  }
  if (t == 1023) row_start[NNODES] = wsum[15];
}

// merged scatter: t < NNODES -> self loop; else graph edge
__global__ void scatter_kernel(const int* __restrict__ ei,
                               int* __restrict__ cursor,
                               int* __restrict__ csr_src,
                               int* __restrict__ csr_dst) {
  int t = blockIdx.x * 256 + threadIdx.x;
  if (t < NNODES) {
    int pos = atomicAdd(&cursor[t], 1);
    csr_src[pos] = t;
    csr_dst[pos] = t;
  } else if (t < ETOT) {
    int e = t - NNODES;
    int d = ei[NEDGES + e];
    int pos = atomicAdd(&cursor[d], 1);
    csr_src[pos] = ei[e];
    csr_dst[pos] = d;
  }
}

// ---------------------------------------------------------------------------
// Pass A: edge weights w = exp(logit). 8 lanes per edge, TWO edges per group
// (16 edges/wave) for doubled memory-level parallelism. Max-free softmax.
// ---------------------------------------------------------------------------
__global__ __launch_bounds__(256) void edge_logits_kernel(
    const short* __restrict__ xlt, const float* __restrict__ att,
    const int* __restrict__ csr_src, const int* __restrict__ csr_dst,
    float* __restrict__ wbuf) {
  __shared__ float att_s[512];  // att_t[c][h]
  for (int i = threadIdx.x; i < 512; i += 256) {
    int c = i >> 3, h = i & 7;
    att_s[i] = (h < 7) ? att[h * 64 + c] : 0.f;
  }
  __syncthreads();
  int lane = threadIdx.x & 63;
  int wid = threadIdx.x >> 6;
  int eo = lane >> 3, cl = lane & 7;
  int base = (blockIdx.x * 4 + wid) * 16;
  int e0 = base + eo;
  int e1 = base + 8 + eo;
  int ec0 = (e0 < ETOT) ? e0 : (ETOT - 1);
  int ec1 = (e1 < ETOT) ? e1 : (ETOT - 1);
  int sA = csr_src[ec0], dA = csr_dst[ec0];
  int sB = csr_src[ec1], dB = csr_dst[ec1];
  const uint4* xlpA = (const uint4*)(xlt + (size_t)sA * HCP);
  const uint4* xrpA = (const uint4*)(xlt + (size_t)dA * HCP + 512);
  const uint4* xlpB = (const uint4*)(xlt + (size_t)sB * HCP);
  const uint4* xrpB = (const uint4*)(xlt + (size_t)dB * HCP + 512);
  float accA[7], accB[7];
  #pragma unroll
  for (int h = 0; h < 7; ++h) { accA[h] = 0.f; accB[h] = 0.f; }
  #pragma unroll
  for (int q = 0; q < 8; ++q) {
    int c = q * 8 + cl;
    uint4 aA = xlpA[c];
    uint4 bA = xrpA[c];
    uint4 aB = xlpB[c];
    uint4 bB = xrpB[c];
    float4 t0 = *(const float4*)&att_s[c * 8];
    float4 t1 = *(const float4*)&att_s[c * 8 + 4];
    // edge A
    {
      float e0v = bf_lo(aA.x) + bf_lo(bA.x);
      float e1v = bf_hi(aA.x) + bf_hi(bA.x);
      float e2v = bf_lo(aA.y) + bf_lo(bA.y);
      float e3v = bf_hi(aA.y) + bf_hi(bA.y);
      float e4v = bf_lo(aA.z) + bf_lo(bA.z);
      float e5v = bf_hi(aA.z) + bf_hi(bA.z);
      float e6v = bf_lo(aA.w) + bf_lo(bA.w);
      e0v = fmaxf(e0v, 0.2f * e0v); e1v = fmaxf(e1v, 0.2f * e1v);
      e2v = fmaxf(e2v, 0.2f * e2v); e3v = fmaxf(e3v, 0.2f * e3v);
      e4v = fmaxf(e4v, 0.2f * e4v); e5v = fmaxf(e5v, 0.2f * e5v);
      e6v = fmaxf(e6v, 0.2f * e6v);
      accA[0] += t0.x * e0v; accA[1] += t0.y * e1v;
      accA[2] += t0.z * e2v; accA[3] += t0.w * e3v;
      accA[4] += t1.x * e4v; accA[5] += t1.y * e5v;
      accA[6] += t1.z * e6v;
    }
    // edge B
    {
      float e0v = bf_lo(aB.x) + bf_lo(bB.x);
      float e1v = bf_hi(aB.x) + bf_hi(bB.x);
      float e2v = bf_lo(aB.y) + bf_lo(bB.y);
      float e3v = bf_hi(aB.y) + bf_hi(bB.y);
      float e4v = bf_lo(aB.z) + bf_lo(bB.z);
      float e5v = bf_hi(aB.z) + bf_hi(bB.z);
      float e6v = bf_lo(aB.w) + bf_lo(bB.w);
      e0v = fmaxf(e0v, 0.2f * e0v); e1v = fmaxf(e1v, 0.2f * e1v);
      e2v = fmaxf(e2v, 0.2f * e2v); e3v = fmaxf(e3v, 0.2f * e3v);
      e4v = fmaxf(e4v, 0.2f * e4v); e5v = fmaxf(e5v, 0.2f * e5v);
      e6v = fmaxf(e6v, 0.2f * e6v);
      accB[0] += t0.x * e0v; accB[1] += t0.y * e1v;
      accB[2] += t0.z * e2v; accB[3] += t0.w * e3v;
      accB[4] += t1.x * e4v; accB[5] += t1.y * e5v;
      accB[6] += t1.z * e6v;
    }
  }
  #pragma unroll
  for (int h = 0; h < 7; ++h) {
    accA[h] += __shfl_xor(accA[h], 1, 64);
    accA[h] += __shfl_xor(accA[h], 2, 64);
    accA[h] += __shfl_xor(accA[h], 4, 64);
    accB[h] += __shfl_xor(accB[h], 1, 64);
    accB[h] += __shfl_xor(accB[h], 2, 64);
    accB[h] += __shfl_xor(accB[h], 4, 64);
  }
  float resA = 0.f, resB = 0.f;
  #pragma unroll
  for (int h = 0; h < 7; ++h) {
    resA = (cl == h) ? accA[h] : resA;
    resB = (cl == h) ? accB[h] : resB;
  }
  float wA = (cl < 7) ? __expf(resA) : 0.f;
  float wB = (cl < 7) ? __expf(resB) : 0.f;
  if (e0 < ETOT) wbuf[(size_t)e0 * 8 + cl] = wA;  // 256B coalesced per wave
  if (e1 < ETOT) wbuf[(size_t)e1 * 8 + cl] = wB;
}

// ---------------------------------------------------------------------------
// Pass B: single-pass aggregation, FOUR waves per node (stride-4 edge split),
// LDS merge. lane = channel. The node's src-index list is loaded per 64-edge
// window with ONE coalesced load and broadcast via __shfl; the inner loop is
// QUAD-unrolled so a wave's entire window share (up to 4 gathers) is in
// flight simultaneously — single latency hop per window.
// FINAL=1 additionally runs the output MLP 64->32->16->9 + log_softmax.
// Grid: 10000 blocks x 256 thr = 1 node/block x 4 waves/node.
// ---------------------------------------------------------------------------
#define AGG_EDGE(wa, wb, xv)                                                   \
  do {                                                                         \
    o0 += (wa).x * bf_lo((xv).x);                                              \
    o1 += (wa).y * bf_hi((xv).x);                                              \
    o2 += (wa).z * bf_lo((xv).y);                                              \
    o3 += (wa).w * bf_hi((xv).y);                                              \
    o4 += (wb).x * bf_lo((xv).z);                                              \
    o5 += (wb).y * bf_hi((xv).z);                                              \
    o6 += (wb).z * bf_lo((xv).w);                                              \
    s0 += (wa).x; s1 += (wa).y; s2 += (wa).z; s3 += (wa).w;                    \
    s4 += (wb).x; s5 += (wb).y; s6 += (wb).z;                                  \
  } while (0)

template <int FINAL>
__global__ __launch_bounds__(256) void gat_agg4_kernel(
    const short* __restrict__ xlt, const float* __restrict__ wbuf,
    const float* __restrict__ cbias, const int* __restrict__ row_start,
    const int* __restrict__ csr_src, short* __restrict__ hout,
    const float* __restrict__ V1, const float* __restrict__ c1,
    const float* __restrict__ V2, const float* __restrict__ c2,
    const float* __restrict__ V3, const float* __restrict__ c3,
    float* __restrict__ out) {
  __shared__ float part[3][14][64];  // partials from waves 1..3
  __shared__ float hb[64], r1m[32], r2m[16], z3m[9];
  int lane = threadIdx.x & 63;
  int wv = threadIdx.x >> 6;  // quarter 0..3
  int n = blockIdx.x;
  int beg = row_start[n], end = row_start[n + 1];
  int deg = end - beg;

  float o0 = 0.f, o1 = 0.f, o2 = 0.f, o3 = 0.f, o4 = 0.f, o5 = 0.f, o6 = 0.f;
  float s0 = 0.f, s1 = 0.f, s2 = 0.f, s3 = 0.f, s4 = 0.f, s5 = 0.f, s6 = 0.f;

  for (int base = 0; base < deg; base += 64) {
    int rem = deg - base;                 // > 0
    int lim = (rem < 64) ? rem : 64;
    // one coalesced load covers this 64-edge window's src indices
    int il = base + ((lane < rem) ? lane : (rem - 1));
    int srcs = csr_src[beg + il];

    int j = base + wv;
    int wend = base + lim;
    // quads: edges j, j+4, j+8, j+12 — all 4 gathers in flight at once
    for (; j + 12 < wend; j += 16) {
      int srcA = __shfl(srcs, j - base, 64);
      int srcB = __shfl(srcs, j + 4 - base, 64);
      int srcC = __shfl(srcs, j + 8 - base, 64);
      int srcD = __shfl(srcs, j + 12 - base, 64);
      int eA = beg + j, eB = eA + 4, eC = eA + 8, eD = eA + 12;
      float4 waA = *(const float4*)&wbuf[(size_t)eA * 8];       // uniform
      float4 wbA = *(const float4*)&wbuf[(size_t)eA * 8 + 4];
      float4 waB = *(const float4*)&wbuf[(size_t)eB * 8];
      float4 wbB = *(const float4*)&wbuf[(size_t)eB * 8 + 4];
      float4 waC = *(const float4*)&wbuf[(size_t)eC * 8];
      float4 wbC = *(const float4*)&wbuf[(size_t)eC * 8 + 4];
      float4 waD = *(const float4*)&wbuf[(size_t)eD * 8];
      float4 wbD = *(const float4*)&wbuf[(size_t)eD * 8 + 4];
      uint4 xvA = *(const uint4*)(xlt + (size_t)srcA * HCP + (size_t)lane * 8);
      uint4 xvB = *(const uint4*)(xlt + (size_t)srcB * HCP + (size_t)lane * 8);
      uint4 xvC = *(const uint4*)(xlt + (size_t)srcC * HCP + (size_t)lane * 8);
      uint4 xvD = *(const uint4*)(xlt + (size_t)srcD * HCP + (size_t)lane * 8);
      AGG_EDGE(waA, wbA, xvA);
      AGG_EDGE(waB, wbB, xvB);
      AGG_EDGE(waC, wbC, xvC);
      AGG_EDGE(waD, wbD, xvD);
    }
    // pair tail
    for (; j + 4 < wend; j += 8) {
      int srcA = __shfl(srcs, j - base, 64);
      int srcB = __shfl(srcs, j + 4 - base, 64);
      int eA = beg + j, eB = eA + 4;
      float4 waA = *(const float4*)&wbuf[(size_t)eA * 8];
      float4 wbA = *(const float4*)&wbuf[(size_t)eA * 8 + 4];
      float4 waB = *(const float4*)&wbuf[(size_t)eB * 8];
      float4 wbB = *(const float4*)&wbuf[(size_t)eB * 8 + 4];
      uint4 xvA = *(const uint4*)(xlt + (size_t)srcA * HCP + (size_t)lane * 8);
      uint4 xvB = *(const uint4*)(xlt + (size_t)srcB * HCP + (size_t)lane * 8);
      AGG_EDGE(waA, wbA, xvA);
      AGG_EDGE(waB, wbB, xvB);
    }
    if (j < wend) {  // single tail edge in this window
      int src = __shfl(srcs, j - base, 64);
      int e = beg + j;
      float4 wa = *(const float4*)&wbuf[(size_t)e * 8];
      float4 wb = *(const float4*)&wbuf[(size_t)e * 8 + 4];
      uint4 xv = *(const uint4*)(xlt + (size_t)src * HCP + (size_t)lane * 8);
      AGG_EDGE(wa, wb, xv);
    }
  }

  if (wv > 0) {
    int p = wv - 1;
    part[p][0][lane] = o0;  part[p][1][lane] = o1;
    part[p][2][lane] = o2;  part[p][3][lane] = o3;
    part[p][4][lane] = o4;  part[p][5][lane] = o5;
    part[p][6][lane] = o6;
    part[p][7][lane] = s0;  part[p][8][lane] = s1;
    part[p][9][lane] = s2;  part[p][10][lane] = s3;
    part[p][11][lane] = s4; part[p][12][lane] = s5;
    part[p][13][lane] = s6;
  }
  __syncthreads();
  if (wv == 0) {
    o0 += part[0][0][lane] + part[1][0][lane] + part[2][0][lane];
    o1 += part[0][1][lane] + part[1][1][lane] + part[2][1][lane];
    o2 += part[0][2][lane] + part[1][2][lane] + part[2][2][lane];
    o3 += part[0][3][lane] + part[1][3][lane] + part[2][3][lane];
    o4 += part[0][4][lane] + part[1][4][lane] + part[2][4][lane];
    o5 += part[0][5][lane] + part[1][5][lane] + part[2][5][lane];
    o6 += part[0][6][lane] + part[1][6][lane] + part[2][6][lane];
    s0 += part[0][7][lane] + part[1][7][lane] + part[2][7][lane];
    s1 += part[0][8][lane] + part[1][8][lane] + part[2][8][lane];
    s2 += part[0][9][lane] + part[1][9][lane] + part[2][9][lane];
    s3 += part[0][10][lane] + part[1][10][lane] + part[2][10][lane];
    s4 += part[0][11][lane] + part[1][11][lane] + part[2][11][lane];
    s5 += part[0][12][lane] + part[1][12][lane] + part[2][12][lane];
    s6 += part[0][13][lane] + part[1][13][lane] + part[2][13][lane];
    float accv = o0 / (s0 + 1e-16f) + o1 / (s1 + 1e-16f) + o2 / (s2 + 1e-16f) +
                 o3 / (s3 + 1e-16f) + o4 / (s4 + 1e-16f) + o5 / (s5 + 1e-16f) +
                 o6 / (s6 + 1e-16f);
    float v = fmaxf(accv * (1.0f / 7.0f) + cbias[lane], 0.f);
    if (!FINAL) {
      hout[(size_t)n * 64 + lane] = f2bf(v);
    } else {
      // ---- output MLP, all within this wave (in-order DS, no barriers) ----
      int t = lane;
      hb[t] = v;
      if (t < 32) {
        float a = c1[t];
        #pragma unroll
        for (int k = 0; k < 64; ++k) a += hb[k] * V1[k * 32 + t];
        r1m[t] = fmaxf(a, 0.f);
      }
      if (t < 16) {
        float a = c2[t];
        #pragma unroll
        for (int k = 0; k < 32; ++k) a += r1m[k] * V2[k * 16 + t];
        r2m[t] = fmaxf(a, 0.f);
      }
      if (t < 9) {
        float a = c3[t];
        #pragma unroll
        for (int k = 0; k < 16; ++k) a += r2m[k] * V3[k * 9 + t];
        z3m[t] = a;
      }
      if (t < 9) {
        float mx = z3m[0];
        #pragma unroll
        for (int k = 1; k < 9; ++k) mx = fmaxf(mx, z3m[k]);
        float s = 0.f;
        #pragma unroll
        for (int k = 0; k < 9; ++k) s += __expf(z3m[k] - mx);
        out[(size_t)n * 9 + t] = z3m[t] - mx - logf(s);
      }
    }
  }
}

// ---------------------------------------------------------------------------
extern "C" void kernel_launch(void* const* d_in, const int* in_sizes, int n_in,
                              void* d_out, int out_size, void* d_ws, size_t ws_size,
                              hipStream_t stream) {
  const float* x   = (const float*)d_in[0];
  const int*   ei  = (const int*)d_in[1];
  const float* W1  = (const float*)d_in[2];
  const float* b1  = (const float*)d_in[3];
  const float* W2  = (const float*)d_in[4];
  const float* b2  = (const float*)d_in[5];
  const float* W3  = (const float*)d_in[6];
  const float* b3  = (const float*)d_in[7];
  const float* Wl  = (const float*)d_in[8];
  const float* bl  = (const float*)d_in[9];
  const float* Wr  = (const float*)d_in[10];
  const float* att = (const float*)d_in[11];
  const float* cb  = (const float*)d_in[12];
  const float* V1  = (const float*)d_in[13];
  const float* c1  = (const float*)d_in[14];
  const float* V2  = (const float*)d_in[15];
  const float* c2  = (const float*)d_in[16];
  const float* V3  = (const float*)d_in[17];
  const float* c3  = (const float*)d_in[18];
  float* out = (float*)d_out;

  char* ws = (char*)d_ws;
  size_t off = 0;
  auto alloc = [&](size_t bytes) {
    void* p = ws + off;
    off = (off + bytes + 255) & ~(size_t)255;
    return p;
  };
  // region0 (reused): xb (20.5MB) -> h2 -> xlt [N][1024] shorts
  char* region0 = (char*)alloc((size_t)NNODES * 1024 * 2 + 1024);
  short* xb  = (short*)region0;
  short* h2  = (short*)region0;
  short* xlt = (short*)region0;
  // region1 (reused): h1 (10.2MB) -> hA/hB
  char* region1 = (char*)alloc((size_t)NNODES * 512 * 2 + 1024);
  short* h1 = (short*)region1;
  short* hA = (short*)region1;
  short* hB = hA + (size_t)NNODES * 64;
  // persistent
  short* W1t = (short*)alloc((size_t)512 * 1024 * 2);
  short* W2t = (short*)alloc((size_t)256 * 512 * 2);
  short* W3t = (short*)alloc((size_t)64 * 256 * 2);
  short* Wgt = (short*)alloc((size_t)5 * HCP * 64 * 2);
  float* bg  = (float*)alloc((size_t)5 * HCP * 4);
  int* cnt       = (int*)alloc((size_t)NNODES * 4);
  int* row_start = (int*)alloc((size_t)(NNODES + 1) * 4);
  int* cursor    = (int*)alloc((size_t)NNODES * 4);
  int* csr_src   = (int*)alloc((size_t)ETOT * 4);
  int* csr_dst   = (int*)alloc((size_t)ETOT * 4);
  float* wbuf    = (float*)alloc((size_t)ETOT * 8 * 4);

  // ---- fused prep (convert + transposes + pack + cnt init)
  prep_kernel<<<(PTOT + 255) / 256, 256, 0, stream>>>(
      x, xb, W1, W1t, W2, W2t, W3, W3t, Wl, Wr, bl, Wgt, bg, cnt);

  // ---- CSR build (self-loops included)
  hist_kernel<<<(NEDGES + 255) / 256, 256, 0, stream>>>(ei, cnt);
  scan_kernel<<<1, 1024, 0, stream>>>(cnt, row_start, cursor);
  scatter_kernel<<<(ETOT + 255) / 256, 256, 0, stream>>>(ei, cursor, csr_src, csr_dst);

  // ---- input MLP (bf16 MFMA)
  mfma_gemm<64, 128, 1><<<dim3(157, 4), 256, 0, stream>>>(
      xb, W1t, b1, h1, NNODES, 1024, 512);
  mfma_gemm<64, 128, 1><<<dim3(157, 2), 256, 0, stream>>>(
      h1, W2t, b2, h2, NNODES, 512, 256);
  mfma_gemm<64, 64, 1><<<dim3(157, 1), 256, 0, stream>>>(
      h2, W3t, b3, hA, NNODES, 256, 64);

  // ---- 5 GATv2 layers
  short* hcur = hA;
  short* hnext = hB;
  for (int layer = 0; layer < 5; ++layer) {
    mfma_gemm<128, 128, 0><<<dim3(79, 8), 256, 0, stream>>>(
        hcur, Wgt + (size_t)layer * HCP * 64, bg + (size_t)layer * HCP, xlt,
        NNODES, 64, HCP);
    edge_logits_kernel<<<(ETOT + 63) / 64, 256, 0, stream>>>(
        xlt, att + (size_t)layer * HC, csr_src, csr_dst, wbuf);
    if (layer < 4) {
      gat_agg4_kernel<0><<<10000, 256, 0, stream>>>(
          xlt, wbuf, cb + (size_t)layer * 64, row_start, csr_src, hnext,
          V1, c1, V2, c2, V3, c3, out);
    } else {
      gat_agg4_kernel<1><<<10000, 256, 0, stream>>>(
          xlt, wbuf, cb + (size_t)layer * 64, row_start, csr_src, hnext,
          V1, c1, V2, c2, V3, c3, out);
    }
    short* tmp = hcur; hcur = hnext; hnext = tmp;
  }
}

// Round 12
// 530.367 us; speedup vs baseline: 1.0535x; 1.0535x over previous
//
#include <hip/hip_runtime.h>
#include <hip/hip_bf16.h>
#include <math.h>

#define NNODES 10000
#define NEDGES 160000
#define ETOT (NEDGES + NNODES)  // edges + self-loops
#define HEADS 7
#define CH 64
#define HC 448    // HEADS*CH
#define HCP 1024  // padded fused width: [xl 512 | xr 512], slot = half*512+c*8+h

typedef __attribute__((ext_vector_type(8))) short short8;
typedef __attribute__((ext_vector_type(4))) float floatx4;

__device__ __forceinline__ float bf_lo(unsigned u) {
  return __uint_as_float(u << 16);
}
__device__ __forceinline__ float bf_hi(unsigned u) {
  return __uint_as_float(u & 0xffff0000u);
}
__device__ __forceinline__ short f2bf(float v) {
  return __bfloat16_as_short(__float2bfloat16(v));
}

// ---------------------------------------------------------------------------
// Fused prep: x->bf16, W1/W2/W3 transpose->bf16, GAT weight pack, cnt init.
// ---------------------------------------------------------------------------
#define P0 2560000                // convert groups (4 floats each)
#define P1 (P0 + 512 * 1024)      // W1t entries
#define P2 (P1 + 256 * 512)      // W2t
#define P3 (P2 + 64 * 256)       // W3t
#define P4 (P3 + 5 * HCP * 64)    // Wgt
#define P5 (P4 + 5 * HCP)         // bg
#define P6 (P5 + NNODES)          // cnt init
#define PTOT P6

__global__ __launch_bounds__(256) void prep_kernel(
    const float* __restrict__ x, short* __restrict__ xb,
    const float* __restrict__ W1, short* __restrict__ W1t,
    const float* __restrict__ W2, short* __restrict__ W2t,
    const float* __restrict__ W3, short* __restrict__ W3t,
    const float* __restrict__ Wl, const float* __restrict__ Wr,
    const float* __restrict__ bl, short* __restrict__ Wgt,
    float* __restrict__ bg, int* __restrict__ cnt) {
  int idx = blockIdx.x * 256 + threadIdx.x;
  if (idx < P0) {
    float4 v = *(const float4*)&x[(size_t)idx * 4];
    short4 o;
    o.x = f2bf(v.x); o.y = f2bf(v.y); o.z = f2bf(v.z); o.w = f2bf(v.w);
    *(short4*)&xb[(size_t)idx * 4] = o;
  } else if (idx < P1) {
    int i = idx - P0;               // W1: K=1024, N=512
    int n = i / 1024, k = i % 1024;
    W1t[i] = f2bf(W1[(size_t)k * 512 + n]);
  } else if (idx < P2) {
    int i = idx - P1;               // W2: K=512, N=256
    int n = i / 512, k = i % 512;
    W2t[i] = f2bf(W2[(size_t)k * 256 + n]);
  } else if (idx < P3) {
    int i = idx - P2;               // W3: K=256, N=64
    int n = i / 256, k = i % 256;
    W3t[i] = f2bf(W3[(size_t)k * 64 + n]);
  } else if (idx < P4) {
    int i = idx - P3;               // Wgt[l][col'][k]
    int l = i / (HCP * 64);
    int rem = i % (HCP * 64);
    int col = rem / 64, k = rem % 64;
    int half = col >> 9;
    int within = col & 511;
    int c = within >> 3, h = within & 7;
    float v = 0.f;
    if (h < 7) {
      const float* W = half ? Wr : Wl;
      v = W[((size_t)l * 64 + k) * HC + h * 64 + c];
    }
    Wgt[i] = f2bf(v);
  } else if (idx < P5) {
    int i = idx - P4;
    int l = i >> 10, col = i & 1023;
    int half = col >> 9, within = col & 511;
    int c = within >> 3, h = within & 7;
    bg[i] = (!half && h < 7) ? bl[(size_t)l * HC + h * 64 + c] : 0.f;
  } else if (idx < P6) {
    cnt[idx - P5] = 1;  // self-loop
  }
}

// ---------------------------------------------------------------------------
// MFMA bf16 GEMM: C = act(A @ Bt^T + bias), bf16 row-major out.
// ---------------------------------------------------------------------------
template <int BM, int BN, int RELU>
__global__ __launch_bounds__(256) void mfma_gemm(
    const short* __restrict__ A, const short* __restrict__ Bt,
    const float* __restrict__ bias, short* __restrict__ C,
    int M, int K, int Nc) {
  __shared__ short As[BM * 64];
  __shared__ short Bs[BN * 64];
  constexpr int MI = BM / 32;
  constexpr int NJ = BN / 32;
  int tid = threadIdx.x;
  int lane = tid & 63, wave = tid >> 6;
  int wm = wave >> 1, wn = wave & 1;
  int row0 = blockIdx.x * BM, col0 = blockIdx.y * BN;
  floatx4 acc[MI][NJ] = {};

  for (int k0 = 0; k0 < K; k0 += 64) {
    #pragma unroll
    for (int i = 0; i < BM / 32; ++i) {
      int c = i * 4 + wave;
      int r = c * 8 + (lane >> 3);
      int k = (lane & 7) * 8;
      int grow = row0 + r;
      if (grow >= M) grow = M - 1;
      __builtin_amdgcn_global_load_lds(
          (const __attribute__((address_space(1))) void*)(A + (size_t)grow * K + k0 + k),
          (__attribute__((address_space(3))) void*)(As + c * 512), 16, 0, 0);
    }
    #pragma unroll
    for (int i = 0; i < BN / 32; ++i) {
      int c = i * 4 + wave;
      int r = c * 8 + (lane >> 3);
      int k = (lane & 7) * 8;
      int gcol = col0 + r;
      if (gcol >= Nc) gcol = Nc - 1;
      __builtin_amdgcn_global_load_lds(
          (const __attribute__((address_space(1))) void*)(Bt + (size_t)gcol * K + k0 + k),
          (__attribute__((address_space(3))) void*)(Bs + c * 512), 16, 0, 0);
    }
    __syncthreads();
    int lr = lane & 15, lq = lane >> 4;
    #pragma unroll
    for (int kk = 0; kk < 64; kk += 32) {
      short8 af[MI], bf[NJ];
      #pragma unroll
      for (int i = 0; i < MI; ++i)
        af[i] = *(const short8*)&As[(wm * (BM / 2) + i * 16 + lr) * 64 + kk + lq * 8];
      #pragma unroll
      for (int j = 0; j < NJ; ++j)
        bf[j] = *(const short8*)&Bs[(wn * (BN / 2) + j * 16 + lr) * 64 + kk + lq * 8];
      #pragma unroll
      for (int i = 0; i < MI; ++i)
        #pragma unroll
        for (int j = 0; j < NJ; ++j)
          acc[i][j] = __builtin_amdgcn_mfma_f32_16x16x32_bf16(
              af[i], bf[j], acc[i][j], 0, 0, 0);
    }
    __syncthreads();
  }

  int lr = lane & 15, lq = lane >> 4;
  #pragma unroll
  for (int j = 0; j < NJ; ++j) {
    int col = col0 + wn * (BN / 2) + j * 16 + lr;
    float bj = bias ? bias[col] : 0.f;
    #pragma unroll
    for (int i = 0; i < MI; ++i) {
      int rbase = row0 + wm * (BM / 2) + i * 16 + lq * 4;
      #pragma unroll
      for (int r = 0; r < 4; ++r) {
        int row = rbase + r;
        if (row < M) {
          float v = acc[i][j][r] + bj;
          if (RELU) v = fmaxf(v, 0.f);
          C[(size_t)row * Nc + col] = f2bf(v);
        }
      }
    }
  }
}

// ---------------------------------------------------------------------------
// CSR build (dst-grouped, self-loops included).
// ---------------------------------------------------------------------------
__global__ void hist_kernel(const int* __restrict__ ei, int* __restrict__ cnt) {
  int e = blockIdx.x * 256 + threadIdx.x;
  if (e < NEDGES) atomicAdd(&cnt[ei[NEDGES + e]], 1);
}

// single-block shuffle-based scan
__global__ __launch_bounds__(1024) void scan_kernel(
    const int* __restrict__ cnt, int* __restrict__ row_start,
    int* __restrict__ cursor) {
  __shared__ int wsum[16];
  int t = threadIdx.x;
  int lane = t & 63, w = t >> 6;
  int base = t * 10;
  int v[10], s = 0;
  #pragma unroll
  for (int i = 0; i < 10; ++i) {
    v[i] = (base + i < NNODES) ? cnt[base + i] : 0;
    s += v[i];
  }
  int incl = s;
  #pragma unroll
  for (int off = 1; off < 64; off <<= 1) {
    int o = __shfl_up(incl, off, 64);
    if (lane >= off) incl += o;
  }
  if (lane == 63) wsum[w] = incl;
  __syncthreads();
  if (w == 0) {
    int wv = (lane < 16) ? wsum[lane] : 0;
    #pragma unroll
    for (int off = 1; off < 16; off <<= 1) {
      int o = __shfl_up(wv, off, 64);
      if (lane >= off) wv += o;
    }
    if (lane < 16) wsum[lane] = wv;
  }
  __syncthreads();
  int woff = (w > 0) ? wsum[w - 1] : 0;
  int excl = woff + incl - s;
  #pragma unroll
  for (int i = 0; i < 10; ++i) {
    if (base + i < NNODES) {
      row_start[base + i] = excl;
      cursor[base + i] = excl;
    }
    excl += v[i];
  }
  if (t == 1023) row_start[NNODES] = wsum[15];
}

// merged scatter: t < NNODES -> self loop; else graph edge
__global__ void scatter_kernel(const int* __restrict__ ei,
                               int* __restrict__ cursor,
                               int* __restrict__ csr_src,
                               int* __restrict__ csr_dst) {
  int t = blockIdx.x * 256 + threadIdx.x;
  if (t < NNODES) {
    int pos = atomicAdd(&cursor[t], 1);
    csr_src[pos] = t;
    csr_dst[pos] = t;
  } else if (t < ETOT) {
    int e = t - NNODES;
    int d = ei[NEDGES + e];
    int pos = atomicAdd(&cursor[d], 1);
    csr_src[pos] = ei[e];
    csr_dst[pos] = d;
  }
}

// ---------------------------------------------------------------------------
// Pass A: edge weights w = exp(logit). 8 lanes per edge, TWO edges per group
// (16 edges/wave) for doubled memory-level parallelism. Max-free softmax.
// ---------------------------------------------------------------------------
__global__ __launch_bounds__(256) void edge_logits_kernel(
    const short* __restrict__ xlt, const float* __restrict__ att,
    const int* __restrict__ csr_src, const int* __restrict__ csr_dst,
    float* __restrict__ wbuf) {
  __shared__ float att_s[512];  // att_t[c][h]
  for (int i = threadIdx.x; i < 512; i += 256) {
    int c = i >> 3, h = i & 7;
    att_s[i] = (h < 7) ? att[h * 64 + c] : 0.f;
  }
  __syncthreads();
  int lane = threadIdx.x & 63;
  int wid = threadIdx.x >> 6;
  int eo = lane >> 3, cl = lane & 7;
  int base = (blockIdx.x * 4 + wid) * 16;
  int e0 = base + eo;
  int e1 = base + 8 + eo;
  int ec0 = (e0 < ETOT) ? e0 : (ETOT - 1);
  int ec1 = (e1 < ETOT) ? e1 : (ETOT - 1);
  int sA = csr_src[ec0], dA = csr_dst[ec0];
  int sB = csr_src[ec1], dB = csr_dst[ec1];
  const uint4* xlpA = (const uint4*)(xlt + (size_t)sA * HCP);
  const uint4* xrpA = (const uint4*)(xlt + (size_t)dA * HCP + 512);
  const uint4* xlpB = (const uint4*)(xlt + (size_t)sB * HCP);
  const uint4* xrpB = (const uint4*)(xlt + (size_t)dB * HCP + 512);
  float accA[7], accB[7];
  #pragma unroll
  for (int h = 0; h < 7; ++h) { accA[h] = 0.f; accB[h] = 0.f; }
  #pragma unroll
  for (int q = 0; q < 8; ++q) {
    int c = q * 8 + cl;
    uint4 aA = xlpA[c];
    uint4 bA = xrpA[c];
    uint4 aB = xlpB[c];
    uint4 bB = xrpB[c];
    float4 t0 = *(const float4*)&att_s[c * 8];
    float4 t1 = *(const float4*)&att_s[c * 8 + 4];
    // edge A
    {
      float e0v = bf_lo(aA.x) + bf_lo(bA.x);
      float e1v = bf_hi(aA.x) + bf_hi(bA.x);
      float e2v = bf_lo(aA.y) + bf_lo(bA.y);
      float e3v = bf_hi(aA.y) + bf_hi(bA.y);
      float e4v = bf_lo(aA.z) + bf_lo(bA.z);
      float e5v = bf_hi(aA.z) + bf_hi(bA.z);
      float e6v = bf_lo(aA.w) + bf_lo(bA.w);
      e0v = fmaxf(e0v, 0.2f * e0v); e1v = fmaxf(e1v, 0.2f * e1v);
      e2v = fmaxf(e2v, 0.2f * e2v); e3v = fmaxf(e3v, 0.2f * e3v);
      e4v = fmaxf(e4v, 0.2f * e4v); e5v = fmaxf(e5v, 0.2f * e5v);
      e6v = fmaxf(e6v, 0.2f * e6v);
      accA[0] += t0.x * e0v; accA[1] += t0.y * e1v;
      accA[2] += t0.z * e2v; accA[3] += t0.w * e3v;
      accA[4] += t1.x * e4v; accA[5] += t1.y * e5v;
      accA[6] += t1.z * e6v;
    }
    // edge B
    {
      float e0v = bf_lo(aB.x) + bf_lo(bB.x);
      float e1v = bf_hi(aB.x) + bf_hi(bB.x);
      float e2v = bf_lo(aB.y) + bf_lo(bB.y);
      float e3v = bf_hi(aB.y) + bf_hi(bB.y);
      float e4v = bf_lo(aB.z) + bf_lo(bB.z);
      float e5v = bf_hi(aB.z) + bf_hi(bB.z);
      float e6v = bf_lo(aB.w) + bf_lo(bB.w);
      e0v = fmaxf(e0v, 0.2f * e0v); e1v = fmaxf(e1v, 0.2f * e1v);
      e2v = fmaxf(e2v, 0.2f * e2v); e3v = fmaxf(e3v, 0.2f * e3v);
      e4v = fmaxf(e4v, 0.2f * e4v); e5v = fmaxf(e5v, 0.2f * e5v);
      e6v = fmaxf(e6v, 0.2f * e6v);
      accB[0] += t0.x * e0v; accB[1] += t0.y * e1v;
      accB[2] += t0.z * e2v; accB[3] += t0.w * e3v;
      accB[4] += t1.x * e4v; accB[5] += t1.y * e5v;
      accB[6] += t1.z * e6v;
    }
  }
  #pragma unroll
  for (int h = 0; h < 7; ++h) {
    accA[h] += __shfl_xor(accA[h], 1, 64);
    accA[h] += __shfl_xor(accA[h], 2, 64);
    accA[h] += __shfl_xor(accA[h], 4, 64);
    accB[h] += __shfl_xor(accB[h], 1, 64);
    accB[h] += __shfl_xor(accB[h], 2, 64);
    accB[h] += __shfl_xor(accB[h], 4, 64);
  }
  float resA = 0.f, resB = 0.f;
  #pragma unroll
  for (int h = 0; h < 7; ++h) {
    resA = (cl == h) ? accA[h] : resA;
    resB = (cl == h) ? accB[h] : resB;
  }
  float wA = (cl < 7) ? __expf(resA) : 0.f;
  float wB = (cl < 7) ? __expf(resB) : 0.f;
  if (e0 < ETOT) wbuf[(size_t)e0 * 8 + cl] = wA;  // 256B coalesced per wave
  if (e1 < ETOT) wbuf[(size_t)e1 * 8 + cl] = wB;
}

// ---------------------------------------------------------------------------
// Pass B: single-pass aggregation, FOUR waves per node (stride-4 edge split),
// LDS merge. lane = channel. The node's src-index list is loaded per 64-edge
// window with ONE coalesced load (lane i -> csr_src[beg+i]) and broadcast via
// __shfl, so the per-iteration index-load -> gather chain disappears: a wave's
// gathers issue back-to-back. Pair-unrolled (2 gathers/iteration).
// FINAL=1 additionally runs the output MLP 64->32->16->9 + log_softmax.
// Grid: 10000 blocks x 256 thr = 1 node/block x 4 waves/node.
// ---------------------------------------------------------------------------
#define AGG_EDGE(wa, wb, xv)                                                   \
  do {                                                                         \
    o0 += (wa).x * bf_lo((xv).x);                                              \
    o1 += (wa).y * bf_hi((xv).x);                                              \
    o2 += (wa).z * bf_lo((xv).y);                                              \
    o3 += (wa).w * bf_hi((xv).y);                                              \
    o4 += (wb).x * bf_lo((xv).z);                                              \
    o5 += (wb).y * bf_hi((xv).z);                                              \
    o6 += (wb).z * bf_lo((xv).w);                                              \
    s0 += (wa).x; s1 += (wa).y; s2 += (wa).z; s3 += (wa).w;                    \
    s4 += (wb).x; s5 += (wb).y; s6 += (wb).z;                                  \
  } while (0)

template <int FINAL>
__global__ __launch_bounds__(256) void gat_agg4_kernel(
    const short* __restrict__ xlt, const float* __restrict__ wbuf,
    const float* __restrict__ cbias, const int* __restrict__ row_start,
    const int* __restrict__ csr_src, short* __restrict__ hout,
    const float* __restrict__ V1, const float* __restrict__ c1,
    const float* __restrict__ V2, const float* __restrict__ c2,
    const float* __restrict__ V3, const float* __restrict__ c3,
    float* __restrict__ out) {
  __shared__ float part[3][14][64];  // partials from waves 1..3
  __shared__ float hb[64], r1m[32], r2m[16], z3m[9];
  int lane = threadIdx.x & 63;
  int wv = threadIdx.x >> 6;  // quarter 0..3
  int n = blockIdx.x;
  int beg = row_start[n], end = row_start[n + 1];
  int deg = end - beg;

  float o0 = 0.f, o1 = 0.f, o2 = 0.f, o3 = 0.f, o4 = 0.f, o5 = 0.f, o6 = 0.f;
  float s0 = 0.f, s1 = 0.f, s2 = 0.f, s3 = 0.f, s4 = 0.f, s5 = 0.f, s6 = 0.f;

  for (int base = 0; base < deg; base += 64) {
    int rem = deg - base;                 // > 0
    int lim = (rem < 64) ? rem : 64;
    // one coalesced load covers this 64-edge window's src indices
    int il = base + ((lane < rem) ? lane : (rem - 1));
    int srcs = csr_src[beg + il];

    int j = base + wv;
    int wend = base + lim;
    // pairs: edges j and j+4 (both src indices via shfl, gathers back-to-back)
    for (; j + 4 < wend; j += 8) {
      int srcA = __shfl(srcs, j - base, 64);
      int srcB = __shfl(srcs, j + 4 - base, 64);
      int eA = beg + j, eB = beg + j + 4;
      float4 waA = *(const float4*)&wbuf[(size_t)eA * 8];       // uniform
      float4 wbA = *(const float4*)&wbuf[(size_t)eA * 8 + 4];
      float4 waB = *(const float4*)&wbuf[(size_t)eB * 8];
      float4 wbB = *(const float4*)&wbuf[(size_t)eB * 8 + 4];
      uint4 xvA = *(const uint4*)(xlt + (size_t)srcA * HCP + (size_t)lane * 8);
      uint4 xvB = *(const uint4*)(xlt + (size_t)srcB * HCP + (size_t)lane * 8);
      AGG_EDGE(waA, wbA, xvA);
      AGG_EDGE(waB, wbB, xvB);
    }
    if (j < wend) {  // single tail edge in this window
      int src = __shfl(srcs, j - base, 64);
      int e = beg + j;
      float4 wa = *(const float4*)&wbuf[(size_t)e * 8];
      float4 wb = *(const float4*)&wbuf[(size_t)e * 8 + 4];
      uint4 xv = *(const uint4*)(xlt + (size_t)src * HCP + (size_t)lane * 8);
      AGG_EDGE(wa, wb, xv);
    }
  }

  if (wv > 0) {
    int p = wv - 1;
    part[p][0][lane] = o0;  part[p][1][lane] = o1;
    part[p][2][lane] = o2;  part[p][3][lane] = o3;
    part[p][4][lane] = o4;  part[p][5][lane] = o5;
    part[p][6][lane] = o6;
    part[p][7][lane] = s0;  part[p][8][lane] = s1;
    part[p][9][lane] = s2;  part[p][10][lane] = s3;
    part[p][11][lane] = s4; part[p][12][lane] = s5;
    part[p][13][lane] = s6;
  }
  __syncthreads();
  if (wv == 0) {
    o0 += part[0][0][lane] + part[1][0][lane] + part[2][0][lane];
    o1 += part[0][1][lane] + part[1][1][lane] + part[2][1][lane];
    o2 += part[0][2][lane] + part[1][2][lane] + part[2][2][lane];
    o3 += part[0][3][lane] + part[1][3][lane] + part[2][3][lane];
    o4 += part[0][4][lane] + part[1][4][lane] + part[2][4][lane];
    o5 += part[0][5][lane] + part[1][5][lane] + part[2][5][lane];
    o6 += part[0][6][lane] + part[1][6][lane] + part[2][6][lane];
    s0 += part[0][7][lane] + part[1][7][lane] + part[2][7][lane];
    s1 += part[0][8][lane] + part[1][8][lane] + part[2][8][lane];
    s2 += part[0][9][lane] + part[1][9][lane] + part[2][9][lane];
    s3 += part[0][10][lane] + part[1][10][lane] + part[2][10][lane];
    s4 += part[0][11][lane] + part[1][11][lane] + part[2][11][lane];
    s5 += part[0][12][lane] + part[1][12][lane] + part[2][12][lane];
    s6 += part[0][13][lane] + part[1][13][lane] + part[2][13][lane];
    float accv = o0 / (s0 + 1e-16f) + o1 / (s1 + 1e-16f) + o2 / (s2 + 1e-16f) +
                 o3 / (s3 + 1e-16f) + o4 / (s4 + 1e-16f) + o5 / (s5 + 1e-16f) +
                 o6 / (s6 + 1e-16f);
    float v = fmaxf(accv * (1.0f / 7.0f) + cbias[lane], 0.f);
    if (!FINAL) {
      hout[(size_t)n * 64 + lane] = f2bf(v);
    } else {
      // ---- output MLP, all within this wave (in-order DS, no barriers) ----
      int t = lane;
      hb[t] = v;
      if (t < 32) {
        float a = c1[t];
        #pragma unroll
        for (int k = 0; k < 64; ++k) a += hb[k] * V1[k * 32 + t];
        r1m[t] = fmaxf(a, 0.f);
      }
      if (t < 16) {
        float a = c2[t];
        #pragma unroll
        for (int k = 0; k < 32; ++k) a += r1m[k] * V2[k * 16 + t];
        r2m[t] = fmaxf(a, 0.f);
      }
      if (t < 9) {
        float a = c3[t];
        #pragma unroll
        for (int k = 0; k < 16; ++k) a += r2m[k] * V3[k * 9 + t];
        z3m[t] = a;
      }
      if (t < 9) {
        float mx = z3m[0];
        #pragma unroll
        for (int k = 1; k < 9; ++k) mx = fmaxf(mx, z3m[k]);
        float s = 0.f;
        #pragma unroll
        for (int k = 0; k < 9; ++k) s += __expf(z3m[k] - mx);
        out[(size_t)n * 9 + t] = z3m[t] - mx - logf(s);
      }
    }
  }
}

// ---------------------------------------------------------------------------
extern "C" void kernel_launch(void* const* d_in, const int* in_sizes, int n_in,
                              void* d_out, int out_size, void* d_ws, size_t ws_size,
                              hipStream_t stream) {
  const float* x   = (const float*)d_in[0];
  const int*   ei  = (const int*)d_in[1];
  const float* W1  = (const float*)d_in[2];
  const float* b1  = (const float*)d_in[3];
  const float* W2  = (const float*)d_in[4];
  const float* b2  = (const float*)d_in[5];
  const float* W3  = (const float*)d_in[6];
  const float* b3  = (const float*)d_in[7];
  const float* Wl  = (const float*)d_in[8];
  const float* bl  = (const float*)d_in[9];
  const float* Wr  = (const float*)d_in[10];
  const float* att = (const float*)d_in[11];
  const float* cb  = (const float*)d_in[12];
  const float* V1  = (const float*)d_in[13];
  const float* c1  = (const float*)d_in[14];
  const float* V2  = (const float*)d_in[15];
  const float* c2  = (const float*)d_in[16];
  const float* V3  = (const float*)d_in[17];
  const float* c3  = (const float*)d_in[18];
  float* out = (float*)d_out;

  char* ws = (char*)d_ws;
  size_t off = 0;
  auto alloc = [&](size_t bytes) {
    void* p = ws + off;
    off = (off + bytes + 255) & ~(size_t)255;
    return p;
  };
  // region0 (reused): xb (20.5MB) -> h2 -> xlt [N][1024] shorts
  char* region0 = (char*)alloc((size_t)NNODES * 1024 * 2 + 1024);
  short* xb  = (short*)region0;
  short* h2  = (short*)region0;
  short* xlt = (short*)region0;
  // region1 (reused): h1 (10.2MB) -> hA/hB
  char* region1 = (char*)alloc((size_t)NNODES * 512 * 2 + 1024);
  short* h1 = (short*)region1;
  short* hA = (short*)region1;
  short* hB = hA + (size_t)NNODES * 64;
  // persistent
  short* W1t = (short*)alloc((size_t)512 * 1024 * 2);
  short* W2t = (short*)alloc((size_t)256 * 512 * 2);
  short* W3t = (short*)alloc((size_t)64 * 256 * 2);
  short* Wgt = (short*)alloc((size_t)5 * HCP * 64 * 2);
  float* bg  = (float*)alloc((size_t)5 * HCP * 4);
  int* cnt       = (int*)alloc((size_t)NNODES * 4);
  int* row_start = (int*)alloc((size_t)(NNODES + 1) * 4);
  int* cursor    = (int*)alloc((size_t)NNODES * 4);
  int* csr_src   = (int*)alloc((size_t)ETOT * 4);
  int* csr_dst   = (int*)alloc((size_t)ETOT * 4);
  float* wbuf    = (float*)alloc((size_t)ETOT * 8 * 4);

  // ---- fused prep (convert + transposes + pack + cnt init)
  prep_kernel<<<(PTOT + 255) / 256, 256, 0, stream>>>(
      x, xb, W1, W1t, W2, W2t, W3, W3t, Wl, Wr, bl, Wgt, bg, cnt);

  // ---- CSR build (self-loops included)
  hist_kernel<<<(NEDGES + 255) / 256, 256, 0, stream>>>(ei, cnt);
  scan_kernel<<<1, 1024, 0, stream>>>(cnt, row_start, cursor);
  scatter_kernel<<<(ETOT + 255) / 256, 256, 0, stream>>>(ei, cursor, csr_src, csr_dst);

  // ---- input MLP (bf16 MFMA)
  mfma_gemm<64, 128, 1><<<dim3(157, 4), 256, 0, stream>>>(
      xb, W1t, b1, h1, NNODES, 1024, 512);
  mfma_gemm<64, 128, 1><<<dim3(157, 2), 256, 0, stream>>>(
      h1, W2t, b2, h2, NNODES, 512, 256);
  mfma_gemm<64, 64, 1><<<dim3(157, 1), 256, 0, stream>>>(
      h2, W3t, b3, hA, NNODES, 256, 64);

  // ---- 5 GATv2 layers
  short* hcur = hA;
  short* hnext = hB;
  for (int layer = 0; layer < 5; ++layer) {
    mfma_gemm<128, 128, 0><<<dim3(79, 8), 256, 0, stream>>>(
        hcur, Wgt + (size_t)layer * HCP * 64, bg + (size_t)layer * HCP, xlt,
        NNODES, 64, HCP);
    edge_logits_kernel<<<(ETOT + 63) / 64, 256, 0, stream>>>(
        xlt, att + (size_t)layer * HC, csr_src, csr_dst, wbuf);
    if (layer < 4) {
      gat_agg4_kernel<0><<<10000, 256, 0, stream>>>(
          xlt, wbuf, cb + (size_t)layer * 64, row_start, csr_src, hnext,
          V1, c1, V2, c2, V3, c3, out);
    } else {
      gat_agg4_kernel<1><<<10000, 256, 0, stream>>>(
          xlt, wbuf, cb + (size_t)layer * 64, row_start, csr_src, hnext,
          V1, c1, V2, c2, V3, c3, out);
    }
    short* tmp = hcur; hcur = hnext; hnext = tmp;
  }
}